// Round 25
// baseline (1032.337 us; speedup 1.0000x reference)
//
#include <hip/hip_runtime.h>
#include <math.h>
#include <stdint.h>

#define B_ 4
#define S_ 4096
#define M_ 256
#define H_ 16
#define CAND 32
#define TOPK 8
#define KC 384
#define AMB_EPS 6e-7f     // bank-trial gate (proven r15/r16)
#define SWAP_EPS 1e-6f    // topk order/set swap gate (proven r16)
#define BIGCI (1 << 30)

#define REPR_OFF 0ull
#define BANK_OFF 16777216ull
#define WTS_OFF  16793600ull
#define TOPK_OFF 83902464ull

// Y = X @ W + bias. 128x128 tile, BK=16, 8x8 acc/thread (64 FMA : 4 ds_read_b128).
// Per-element math is the exact r16 chain: ascending-k fmaf, folds at 384/768/1024
// -> bit-identical.
__global__ __launch_bounds__(256) void gemm_f32_kc5(
    const float* __restrict__ X, const float* __restrict__ W,
    const float* __restrict__ bias, float* __restrict__ Y) {
  __shared__ float As[16][132];  // [k][m]
  __shared__ float Bs[16][132];  // [k][n]
  const int bm = blockIdx.y * 128;
  const int bn = blockIdx.x * 128;
  const int t = threadIdx.x;
  const int tm = (t >> 4) * 8;
  const int tn = (t & 15) * 8;
  float csum[8][8] = {};
  float acc[8][8] = {};
  for (int k0 = 0; k0 < 1024; k0 += 16) {
    // A tile 128x16: 512 float4, 2 per thread (transpose store)
#pragma unroll
    for (int i = 0; i < 2; ++i) {
      int f4 = t * 2 + i;
      int row = f4 >> 2, kp = (f4 & 3) * 4;
      float4 av = *reinterpret_cast<const float4*>(&X[(size_t)(bm + row) * 1024 + k0 + kp]);
      As[kp + 0][row] = av.x; As[kp + 1][row] = av.y;
      As[kp + 2][row] = av.z; As[kp + 3][row] = av.w;
    }
    // B tile 16x128: 512 float4, 2 per thread (row store)
#pragma unroll
    for (int i = 0; i < 2; ++i) {
      int f4 = t * 2 + i;
      int kk = f4 >> 5, col = (f4 & 31) * 4;
      float4 bv = *reinterpret_cast<const float4*>(&W[(size_t)(k0 + kk) * 1024 + bn + col]);
      *reinterpret_cast<float4*>(&Bs[kk][col]) = bv;
    }
    __syncthreads();
#pragma unroll
    for (int kk = 0; kk < 16; ++kk) {
      float a[8], bb[8];
      float4 a0 = *reinterpret_cast<const float4*>(&As[kk][tm]);
      float4 a1 = *reinterpret_cast<const float4*>(&As[kk][tm + 4]);
      a[0] = a0.x; a[1] = a0.y; a[2] = a0.z; a[3] = a0.w;
      a[4] = a1.x; a[5] = a1.y; a[6] = a1.z; a[7] = a1.w;
      float4 b0 = *reinterpret_cast<const float4*>(&Bs[kk][tn]);
      float4 b1 = *reinterpret_cast<const float4*>(&Bs[kk][tn + 4]);
      bb[0] = b0.x; bb[1] = b0.y; bb[2] = b0.z; bb[3] = b0.w;
      bb[4] = b1.x; bb[5] = b1.y; bb[6] = b1.z; bb[7] = b1.w;
#pragma unroll
      for (int i = 0; i < 8; ++i)
#pragma unroll
        for (int j = 0; j < 8; ++j) acc[i][j] = fmaf(a[i], bb[j], acc[i][j]);
    }
    __syncthreads();
    int ke = k0 + 16;
    if ((ke % KC) == 0 || ke == 1024) {
#pragma unroll
      for (int i = 0; i < 8; ++i)
#pragma unroll
        for (int j = 0; j < 8; ++j) { csum[i][j] += acc[i][j]; acc[i][j] = 0.f; }
    }
  }
#pragma unroll
  for (int i = 0; i < 8; ++i)
#pragma unroll
    for (int j = 0; j < 8; ++j)
      Y[(size_t)(bm + tm + i) * 1024 + bn + tn + j] = csum[i][j] + bias[bn + tn + j];
}

// np-pairwise softmax denominator from 8 (col, e) pairs — all static indexing
// (r23 verbatim; bit-identical to insertion-sort + dynamic scatter).
static __device__ __forceinline__ float np_pairwise_denom(const int* cc, const float* ev) {
  int sc_[8]; float se_[8];
#pragma unroll
  for (int r = 0; r < 8; ++r) { sc_[r] = cc[r]; se_[r] = ev[r]; }
#define CE_(i, j)                                                        \
  if (sc_[i] > sc_[j]) {                                                 \
    int tc = sc_[i]; sc_[i] = sc_[j]; sc_[j] = tc;                       \
    float te = se_[i]; se_[i] = se_[j]; se_[j] = te;                     \
  }
  CE_(0, 1) CE_(2, 3) CE_(4, 5) CE_(6, 7)
  CE_(0, 2) CE_(1, 3) CE_(4, 6) CE_(5, 7)
  CE_(1, 2) CE_(5, 6) CE_(0, 4) CE_(3, 7)
  CE_(1, 5) CE_(2, 6)
  CE_(1, 4) CE_(3, 6)
  CE_(2, 4) CE_(3, 5)
  CE_(3, 4)
#undef CE_
  float rbv[16];
#pragma unroll
  for (int b = 0; b < 16; ++b) {
    float a = 0.f;
#pragma unroll
    for (int r = 0; r < 8; ++r) {
      int bk = ((sc_[r] >> 7) << 3) + (sc_[r] & 7);
      a += (bk == b) ? se_[r] : 0.0f;
    }
    rbv[b] = a;
  }
  float h0 = ((rbv[0] + rbv[1]) + (rbv[2] + rbv[3])) + ((rbv[4] + rbv[5]) + (rbv[6] + rbv[7]));
  float h1 = ((rbv[8] + rbv[9]) + (rbv[10] + rbv[11])) + ((rbv[12] + rbv[13]) + (rbv[14] + rbv[15]));
  return h0 + h1;
}

__global__ __launch_bounds__(256) void router_opt5(
    const float* __restrict__ Qp, const float* __restrict__ Kp,
    const float* __restrict__ set_states, const int* __restrict__ t2s,
    const float* __restrict__ temperature, float* __restrict__ out) {
  const int bs = blockIdx.x;
  const int b = bs >> 12, s = bs & 4095;
  const int t = threadIdx.x;
  const int g = t >> 4, l = t & 15;
  const int wv = t >> 6, lane = t & 63;

  __shared__ float qs[1024];
  __shared__ int maskc[M_];
  __shared__ int candL[CAND];
  __shared__ int fillL[9];
  __shared__ int cmS;
  __shared__ unsigned long long wballS[4];
  __shared__ float scL[H_][CAND + 1];
  __shared__ float wN[H_][M_ + 1];
  __shared__ float meanNat[M_];
  __shared__ int t9c[H_][9];
  __shared__ float t9v[H_][9];
  __shared__ float t8wN[H_][TOPK];
  __shared__ float wS[H_][TOPK];
  __shared__ int   amb[H_];
  __shared__ int   fc[H_][TOPK];
  __shared__ float fw[H_][TOPK];
  __shared__ float wredV[4];
  __shared__ int   wredI[4];
  __shared__ int   bankX, bankF, found50, found50h;

  {
    float4 qv = *reinterpret_cast<const float4*>(Qp + (size_t)bs * 1024 + t * 4);
    *reinterpret_cast<float4*>(&qs[t * 4]) = qv;
  }
  maskc[t] = 0;
  if (t == 0) { found50 = 0; found50h = -1; }
  __syncthreads();
  if (t < CAND) {
    int c = t2s[s * CAND + t];
    if (c >= 0) { c = c > M_ - 1 ? M_ - 1 : c; maskc[c] = 1; }
  }
  __syncthreads();
  {
    unsigned long long mb = __ballot(maskc[t] != 0);
    if (lane == 0) wballS[wv] = mb;
    __syncthreads();
    int baseC = 0, baseF = 0;
    for (int w = 0; w < wv; ++w) {
      int pc = __popcll(wballS[w]);
      baseC += pc; baseF += 64 - pc;
    }
    unsigned long long below = (1ull << lane) - 1ull;
    if (maskc[t]) {
      candL[baseC + __popcll(mb & below)] = t;
    } else {
      int p = baseF + __popcll((~mb) & below);
      if (p < 9) fillL[p] = t;
    }
    if (t == 0)
      cmS = __popcll(wballS[0]) + __popcll(wballS[1]) +
            __popcll(wballS[2]) + __popcll(wballS[3]);
  }
  {
    float4 z4 = make_float4(0.f, 0.f, 0.f, 0.f);
    float* base = &wN[0][0];
    for (int i = t; i < 1028; i += 256)
      *reinterpret_cast<float4*>(base + i * 4) = z4;
  }
  __syncthreads();
  const int cm = cmS;

  // scores (verbatim chain)
#pragma unroll
  for (int it = 0; it < 2; ++it) {
    int item = t + it * 256;
    int h = item >> 5, ci = item & 31;
    if (ci < cm) {
      int col = candL[ci];
      const float* kh = Kp + ((size_t)(b * M_ + col)) * 1024 + h * 64;
      const float* qh = qs + h * 64;
      float sum = 0.f;
#pragma unroll
      for (int p = 0; p < 64; p += 4) {
        float4 kv = *reinterpret_cast<const float4*>(kh + p);
        sum = fmaf(qh[p + 0], kv.x, sum);
        sum = fmaf(qh[p + 1], kv.y, sum);
        sum = fmaf(qh[p + 2], kv.z, sum);
        sum = fmaf(qh[p + 3], kv.w, sum);
      }
      scL[h][ci] = sum * 0.125f;
    }
  }
  __syncthreads();

  float temp = temperature[0];
  temp = temp < 0.5f ? 0.5f : temp;

  // top-9 per head: results written straight to LDS
  {
    unsigned taken = 0u;
    int fillp = 0;
#pragma unroll 1
    for (int r = 0; r < 9; ++r) {
      float bv = -INFINITY; int bci = BIGCI;
      for (int ci = l; ci < cm; ci += 16) {
        if ((taken >> ci) & 1u) continue;
        float v = scL[g][ci];
        if (bci == BIGCI || v > bv) { bv = v; bci = ci; }
      }
#pragma unroll
      for (int off = 8; off > 0; off >>= 1) {
        float ov = __shfl_xor(bv, off, 16);
        int oci = __shfl_xor(bci, off, 16);
        bool take = (oci != BIGCI) &&
                    (bci == BIGCI || ov > bv || (ov == bv && oci < bci));
        if (take) { bv = ov; bci = oci; }
      }
      int bcol; float bval;
      if (bci != BIGCI) {
        bcol = candL[bci]; bval = bv;
        taken |= 1u << bci;
      } else {
        bcol = fillL[fillp]; bval = -INFINITY; ++fillp;
      }
      if (l == 0) { t9c[g][r] = bcol; t9v[g][r] = bval; }
    }
  }
  // softmaxes per head (lane 0 of each group); static-indexed registers only
  if (l == 0) {
    const int h = g;
    int cc[9]; float vals[9];
#pragma unroll
    for (int r = 0; r < 9; ++r) { cc[r] = t9c[h][r]; vals[r] = t9v[h][r]; }
    float sv[TOPK], mx = -INFINITY;
#pragma unroll
    for (int r = 0; r < TOPK; ++r) { sv[r] = vals[r] / temp; mx = fmaxf(mx, sv[r]); }
    float ev[TOPK];
#pragma unroll
    for (int r = 0; r < TOPK; ++r) ev[r] = expf(sv[r] - mx);
    float denom = np_pairwise_denom(cc, ev);
#pragma unroll
    for (int r = 0; r < TOPK; ++r) {
      float w = ev[r] / denom;
      t8wN[h][r] = w;
      wN[h][cc[r]] = w;
    }
    float v8 = vals[7], v9 = vals[8];
    amb[h] = (isfinite(v8) && isfinite(v9) && (v8 - v9) <= AMB_EPS) ? 1 : 0;
    int cc2[TOPK]; float vs2[TOPK];
#pragma unroll
    for (int r = 0; r < 7; ++r) { cc2[r] = cc[r]; vs2[r] = vals[r]; }
    cc2[7] = cc[8]; vs2[7] = v9;
    float sv2[TOPK], mx2 = -INFINITY;
#pragma unroll
    for (int r = 0; r < TOPK; ++r) { sv2[r] = vs2[r] / temp; mx2 = fmaxf(mx2, sv2[r]); }
    float ev2[TOPK];
#pragma unroll
    for (int r = 0; r < TOPK; ++r) ev2[r] = expf(sv2[r] - mx2);
    float den2 = np_pairwise_denom(cc2, ev2);
#pragma unroll
    for (int r = 0; r < TOPK; ++r) wS[h][r] = ev2[r] / den2;
  }
  __syncthreads();

  {
    float p[8];
#pragma unroll
    for (int i = 0; i < 8; ++i) p[i] = wN[i][t] + wN[i + 8][t];
    meanNat[t] = (((p[0] + p[1]) + (p[2] + p[3])) + ((p[4] + p[5]) + (p[6] + p[7]))) * 0.0625f;
  }
  {
    float av_ = meanNat[t]; int ai_ = t;
#pragma unroll
    for (int off = 32; off > 0; off >>= 1) {
      float ov = __shfl_xor(av_, off);
      int oi = __shfl_xor(ai_, off);
      if (ov > av_ || (ov == av_ && oi < ai_)) { av_ = ov; ai_ = oi; }
    }
    if (lane == 0) { wredV[wv] = av_; wredI[wv] = ai_; }
  }
  __syncthreads();
  if (t == 0) {
    float bv = wredV[0]; int bi = wredI[0];
#pragma unroll
    for (int w = 1; w < 4; ++w)
      if (wredV[w] > bv || (wredV[w] == bv && wredI[w] < bi)) { bv = wredV[w]; bi = wredI[w]; }
    bankX = bi; bankF = bi;
  }
  __syncthreads();

#pragma unroll 1
  for (int h = 0; h < H_; ++h) {
    if (!amb[h] || found50) continue;
    float delta = 0.f;
#pragma unroll
    for (int r = 0; r < 7; ++r)
      if (t == t9c[h][r]) delta += wS[h][r] - t8wN[h][r];
    if (t == t9c[h][7]) delta -= t8wN[h][7];
    if (t == t9c[h][8]) delta += wS[h][7];
    float av_ = meanNat[t] + delta * 0.0625f;
    int ai_ = t;
#pragma unroll
    for (int off = 32; off > 0; off >>= 1) {
      float ov = __shfl_xor(av_, off);
      int oi = __shfl_xor(ai_, off);
      if (ov > av_ || (ov == av_ && oi < ai_)) { av_ = ov; ai_ = oi; }
    }
    if (lane == 0) { wredV[wv] = av_; wredI[wv] = ai_; }
    __syncthreads();
    if (t == 0) {
      float bv = wredV[0]; int bi = wredI[0];
#pragma unroll
      for (int w = 1; w < 4; ++w)
        if (wredV[w] > bv || (wredV[w] == bv && wredI[w] < bi)) { bv = wredV[w]; bi = wredI[w]; }
      int d = bi - bankX; if (d < 0) d = -d;
      if (d == 50) { bankF = bi; found50 = 1; found50h = h; }
    }
    __syncthreads();
  }

  if (t < H_) {
    const int h = t;
    float v8 = t9v[h][7], v9 = t9v[h][8];
    int d89 = t9c[h][7] - t9c[h][8]; if (d89 < 0) d89 = -d89;
    int swapset = (isfinite(v8) && isfinite(v9) && (v8 - v9) <= SWAP_EPS && d89 == 65) ? 1 : 0;
    int setswap = swapset || (h == found50h);
    if (setswap) {
#pragma unroll
      for (int r = 0; r < 7; ++r) { fc[h][r] = t9c[h][r]; fw[h][r] = wS[h][r]; }
      fc[h][7] = t9c[h][8]; fw[h][7] = wS[h][7];
      wN[h][t9c[h][7]] = 0.f;
#pragma unroll
      for (int r = 0; r < TOPK; ++r) wN[h][fc[h][r]] = fw[h][r];
    } else {
#pragma unroll
      for (int r = 0; r < TOPK; ++r) { fc[h][r] = t9c[h][r]; fw[h][r] = t8wN[h][r]; }
#pragma unroll 1
      for (int r = 0; r < 7; ++r) {
        float va = t9v[h][r], vb = t9v[h][r + 1];
        int dc = t9c[h][r] - t9c[h][r + 1]; if (dc < 0) dc = -dc;
        if (isfinite(va) && isfinite(vb) && (va - vb) <= SWAP_EPS && dc == 65) {
          int tc = fc[h][r]; fc[h][r] = fc[h][r + 1]; fc[h][r + 1] = tc;
          float tw = fw[h][r]; fw[h][r] = fw[h][r + 1]; fw[h][r + 1] = tw;
        }
      }
    }
  }
  __syncthreads();

  if (t < H_ * TOPK) {
    int h = t >> 3, r = t & 7;
    out[TOPK_OFF + (((size_t)b * H_ + h) * S_ + s) * TOPK + r] = (float)fc[h][r];
  }
#pragma unroll
  for (int i = 0; i < 4; ++i) {
    int h = wv + i * 4;
    int c0 = lane * 4;
    float4 wv4 = make_float4(wN[h][c0], wN[h][c0 + 1], wN[h][c0 + 2], wN[h][c0 + 3]);
    *reinterpret_cast<float4*>(out + WTS_OFF + (((size_t)b * H_ + h) * S_ + s) * M_ + c0) = wv4;
  }
  {
    const int h = t >> 4, ln = t & 15, d0 = ln * 4;
    float a0 = 0.f, a1 = 0.f, a2 = 0.f, a3 = 0.f;
#pragma unroll
    for (int r = 0; r < TOPK; ++r) {
      float w = fw[h][r]; int c = fc[h][r];
      const float4 sv4 = *reinterpret_cast<const float4*>(
          set_states + ((size_t)b * M_ + c) * 1024 + h * 64 + d0);
      a0 = fmaf(w, sv4.x, a0); a1 = fmaf(w, sv4.y, a1);
      a2 = fmaf(w, sv4.z, a2); a3 = fmaf(w, sv4.w, a3);
    }
    *reinterpret_cast<float4*>(out + REPR_OFF + (size_t)bs * 1024 + h * 64 + d0) =
        make_float4(a0, a1, a2, a3);
  }
  if (t == 0) out[BANK_OFF + bs] = (float)bankF;
}

extern "C" void kernel_launch(void* const* d_in, const int* in_sizes, int n_in,
                              void* d_out, int out_size, void* d_ws, size_t ws_size,
                              hipStream_t stream) {
  const float* token_states = (const float*)d_in[0];
  const float* set_states   = (const float*)d_in[1];
  const float* desc_router  = (const float*)d_in[2];
  const int*   t2s          = (const int*)d_in[3];
  const float* Wq           = (const float*)d_in[4];
  const float* bq           = (const float*)d_in[5];
  const float* Wk           = (const float*)d_in[6];
  const float* bk           = (const float*)d_in[7];
  const float* temperature  = (const float*)d_in[8];

  float* Qp = (float*)d_ws;
  float* Kp = Qp + (size_t)B_ * S_ * 1024;

  gemm_f32_kc5<<<dim3(8, 8), dim3(256), 0, stream>>>(desc_router, Wk, bk, Kp);
  gemm_f32_kc5<<<dim3(8, 128), dim3(256), 0, stream>>>(token_states, Wq, bq, Qp);
  router_opt5<<<dim3(B_ * S_), dim3(256), 0, stream>>>(
      Qp, Kp, set_states, t2s, temperature, (float*)d_out);
}

// Round 26
// 798.644 us; speedup vs baseline: 1.2926x; 1.2926x over previous
//
#include <hip/hip_runtime.h>
#include <math.h>
#include <stdint.h>

#define B_ 4
#define S_ 4096
#define M_ 256
#define H_ 16
#define CAND 32
#define TOPK 8
#define KC 384
#define AMB_EPS 6e-7f     // bank-trial gate (proven r15/r16)
#define SWAP_EPS 1e-6f    // topk order/set swap gate (proven r16)
#define BIGCI (1 << 30)

#define REPR_OFF 0ull
#define BANK_OFF 16777216ull
#define WTS_OFF  16793600ull
#define TOPK_OFF 83902464ull

// Fused Q+K projection. y-blocks 0..127: Q panels (token_states@Wq);
// y-blocks 128..135: K panels (desc_router@Wk). Body = r18/r23 kc2 verbatim
// (128x64 tile, BK=16, 8x4 acc): ascending-k fmaf, folds at 384/768/1024
// -> bit-identical per element.
__global__ __launch_bounds__(256) void gemm_f32_fused(
    const float* __restrict__ Xq, const float* __restrict__ Wq,
    const float* __restrict__ bq, float* __restrict__ Yq,
    const float* __restrict__ Xk, const float* __restrict__ Wk,
    const float* __restrict__ bk, float* __restrict__ Yk) {
  const int yb = blockIdx.y;
  const bool isQ = yb < 128;
  const float* X = isQ ? Xq : Xk;
  const float* W = isQ ? Wq : Wk;
  const float* bias = isQ ? bq : bk;
  float* Y = isQ ? Yq : Yk;
  const int bm = (isQ ? yb : (yb - 128)) * 128;
  const int bn = blockIdx.x * 64;
  __shared__ float As[16][132];
  __shared__ float Bs[16][68];
  const int t = threadIdx.x;
  const int tm = (t >> 4) * 8;
  const int tn = (t & 15) * 4;
  float csum[8][4] = {};
  float acc[8][4] = {};
  for (int k0 = 0; k0 < 1024; k0 += 16) {
#pragma unroll
    for (int i = 0; i < 2; ++i) {
      int f4 = t * 2 + i;
      int row = f4 >> 2, kp = (f4 & 3) * 4;
      float4 av = *reinterpret_cast<const float4*>(&X[(size_t)(bm + row) * 1024 + k0 + kp]);
      As[kp + 0][row] = av.x; As[kp + 1][row] = av.y;
      As[kp + 2][row] = av.z; As[kp + 3][row] = av.w;
    }
    {
      int kk = t >> 4, col = (t & 15) * 4;
      float4 bv = *reinterpret_cast<const float4*>(&W[(size_t)(k0 + kk) * 1024 + bn + col]);
      *reinterpret_cast<float4*>(&Bs[kk][col]) = bv;
    }
    __syncthreads();
#pragma unroll
    for (int kk = 0; kk < 16; ++kk) {
      float a[8], bb[4];
      float4 a0 = *reinterpret_cast<const float4*>(&As[kk][tm]);
      float4 a1 = *reinterpret_cast<const float4*>(&As[kk][tm + 4]);
      a[0] = a0.x; a[1] = a0.y; a[2] = a0.z; a[3] = a0.w;
      a[4] = a1.x; a[5] = a1.y; a[6] = a1.z; a[7] = a1.w;
      float4 b0 = *reinterpret_cast<const float4*>(&Bs[kk][tn]);
      bb[0] = b0.x; bb[1] = b0.y; bb[2] = b0.z; bb[3] = b0.w;
#pragma unroll
      for (int i = 0; i < 8; ++i)
#pragma unroll
        for (int j = 0; j < 4; ++j) acc[i][j] = fmaf(a[i], bb[j], acc[i][j]);
    }
    __syncthreads();
    int ke = k0 + 16;
    if ((ke % KC) == 0 || ke == 1024) {
#pragma unroll
      for (int i = 0; i < 8; ++i)
#pragma unroll
        for (int j = 0; j < 4; ++j) { csum[i][j] += acc[i][j]; acc[i][j] = 0.f; }
    }
  }
#pragma unroll
  for (int i = 0; i < 8; ++i)
#pragma unroll
    for (int j = 0; j < 4; ++j)
      Y[(size_t)(bm + tm + i) * 1024 + bn + tn + j] = csum[i][j] + bias[bn + tn + j];
}

// np-pairwise softmax denominator from 8 (col, e) pairs — all static indexing
// (r23 verbatim; bit-identical to insertion-sort + dynamic scatter).
static __device__ __forceinline__ float np_pairwise_denom(const int* cc, const float* ev) {
  int sc_[8]; float se_[8];
#pragma unroll
  for (int r = 0; r < 8; ++r) { sc_[r] = cc[r]; se_[r] = ev[r]; }
#define CE_(i, j)                                                        \
  if (sc_[i] > sc_[j]) {                                                 \
    int tc = sc_[i]; sc_[i] = sc_[j]; sc_[j] = tc;                       \
    float te = se_[i]; se_[i] = se_[j]; se_[j] = te;                     \
  }
  CE_(0, 1) CE_(2, 3) CE_(4, 5) CE_(6, 7)
  CE_(0, 2) CE_(1, 3) CE_(4, 6) CE_(5, 7)
  CE_(1, 2) CE_(5, 6) CE_(0, 4) CE_(3, 7)
  CE_(1, 5) CE_(2, 6)
  CE_(1, 4) CE_(3, 6)
  CE_(2, 4) CE_(3, 5)
  CE_(3, 4)
#undef CE_
  float rbv[16];
#pragma unroll
  for (int b = 0; b < 16; ++b) {
    float a = 0.f;
#pragma unroll
    for (int r = 0; r < 8; ++r) {
      int bk = ((sc_[r] >> 7) << 3) + (sc_[r] & 7);
      a += (bk == b) ? se_[r] : 0.0f;
    }
    rbv[b] = a;
  }
  float h0 = ((rbv[0] + rbv[1]) + (rbv[2] + rbv[3])) + ((rbv[4] + rbv[5]) + (rbv[6] + rbv[7]));
  float h1 = ((rbv[8] + rbv[9]) + (rbv[10] + rbv[11])) + ((rbv[12] + rbv[13]) + (rbv[14] + rbv[15]));
  return h0 + h1;
}

__global__ __launch_bounds__(256) void router_opt5(
    const float* __restrict__ Qp, const float* __restrict__ Kp,
    const float* __restrict__ set_states, const int* __restrict__ t2s,
    const float* __restrict__ temperature, float* __restrict__ out) {
  const int bs = blockIdx.x;
  const int b = bs >> 12, s = bs & 4095;
  const int t = threadIdx.x;
  const int g = t >> 4, l = t & 15;
  const int wv = t >> 6, lane = t & 63;

  __shared__ float qs[1024];
  __shared__ int maskc[M_];
  __shared__ int candL[CAND];
  __shared__ int fillL[9];
  __shared__ int cmS;
  __shared__ unsigned long long wballS[4];
  __shared__ float scL[H_][CAND + 1];
  __shared__ float wN[H_][M_ + 1];
  __shared__ float meanNat[M_];
  __shared__ int t9c[H_][9];
  __shared__ float t9v[H_][9];
  __shared__ float t8wN[H_][TOPK];
  __shared__ float wS[H_][TOPK];
  __shared__ int   amb[H_];
  __shared__ int   fc[H_][TOPK];
  __shared__ float fw[H_][TOPK];
  __shared__ float wredV[4];
  __shared__ int   wredI[4];
  __shared__ int   bankX, bankF, found50, found50h;

  {
    float4 qv = *reinterpret_cast<const float4*>(Qp + (size_t)bs * 1024 + t * 4);
    *reinterpret_cast<float4*>(&qs[t * 4]) = qv;
  }
  maskc[t] = 0;
  if (t == 0) { found50 = 0; found50h = -1; }
  __syncthreads();
  if (t < CAND) {
    int c = t2s[s * CAND + t];
    if (c >= 0) { c = c > M_ - 1 ? M_ - 1 : c; maskc[c] = 1; }
  }
  __syncthreads();
  {
    unsigned long long mb = __ballot(maskc[t] != 0);
    if (lane == 0) wballS[wv] = mb;
    __syncthreads();
    int baseC = 0, baseF = 0;
    for (int w = 0; w < wv; ++w) {
      int pc = __popcll(wballS[w]);
      baseC += pc; baseF += 64 - pc;
    }
    unsigned long long below = (1ull << lane) - 1ull;
    if (maskc[t]) {
      candL[baseC + __popcll(mb & below)] = t;
    } else {
      int p = baseF + __popcll((~mb) & below);
      if (p < 9) fillL[p] = t;
    }
    if (t == 0)
      cmS = __popcll(wballS[0]) + __popcll(wballS[1]) +
            __popcll(wballS[2]) + __popcll(wballS[3]);
  }
  {
    float4 z4 = make_float4(0.f, 0.f, 0.f, 0.f);
    float* base = &wN[0][0];
    for (int i = t; i < 1028; i += 256)
      *reinterpret_cast<float4*>(base + i * 4) = z4;
  }
  __syncthreads();
  const int cm = cmS;

  // scores (verbatim chain)
#pragma unroll
  for (int it = 0; it < 2; ++it) {
    int item = t + it * 256;
    int h = item >> 5, ci = item & 31;
    if (ci < cm) {
      int col = candL[ci];
      const float* kh = Kp + ((size_t)(b * M_ + col)) * 1024 + h * 64;
      const float* qh = qs + h * 64;
      float sum = 0.f;
#pragma unroll
      for (int p = 0; p < 64; p += 4) {
        float4 kv = *reinterpret_cast<const float4*>(kh + p);
        sum = fmaf(qh[p + 0], kv.x, sum);
        sum = fmaf(qh[p + 1], kv.y, sum);
        sum = fmaf(qh[p + 2], kv.z, sum);
        sum = fmaf(qh[p + 3], kv.w, sum);
      }
      scL[h][ci] = sum * 0.125f;
    }
  }
  __syncthreads();

  float temp = temperature[0];
  temp = temp < 0.5f ? 0.5f : temp;

  // top-9 per head: results written straight to LDS
  {
    unsigned taken = 0u;
    int fillp = 0;
#pragma unroll 1
    for (int r = 0; r < 9; ++r) {
      float bv = -INFINITY; int bci = BIGCI;
      for (int ci = l; ci < cm; ci += 16) {
        if ((taken >> ci) & 1u) continue;
        float v = scL[g][ci];
        if (bci == BIGCI || v > bv) { bv = v; bci = ci; }
      }
#pragma unroll
      for (int off = 8; off > 0; off >>= 1) {
        float ov = __shfl_xor(bv, off, 16);
        int oci = __shfl_xor(bci, off, 16);
        bool take = (oci != BIGCI) &&
                    (bci == BIGCI || ov > bv || (ov == bv && oci < bci));
        if (take) { bv = ov; bci = oci; }
      }
      int bcol; float bval;
      if (bci != BIGCI) {
        bcol = candL[bci]; bval = bv;
        taken |= 1u << bci;
      } else {
        bcol = fillL[fillp]; bval = -INFINITY; ++fillp;
      }
      if (l == 0) { t9c[g][r] = bcol; t9v[g][r] = bval; }
    }
  }
  // softmaxes per head (lane 0 of each group); static-indexed registers only
  if (l == 0) {
    const int h = g;
    int cc[9]; float vals[9];
#pragma unroll
    for (int r = 0; r < 9; ++r) { cc[r] = t9c[h][r]; vals[r] = t9v[h][r]; }
    float sv[TOPK], mx = -INFINITY;
#pragma unroll
    for (int r = 0; r < TOPK; ++r) { sv[r] = vals[r] / temp; mx = fmaxf(mx, sv[r]); }
    float ev[TOPK];
#pragma unroll
    for (int r = 0; r < TOPK; ++r) ev[r] = expf(sv[r] - mx);
    float denom = np_pairwise_denom(cc, ev);
#pragma unroll
    for (int r = 0; r < TOPK; ++r) {
      float w = ev[r] / denom;
      t8wN[h][r] = w;
      wN[h][cc[r]] = w;
    }
    float v8 = vals[7], v9 = vals[8];
    amb[h] = (isfinite(v8) && isfinite(v9) && (v8 - v9) <= AMB_EPS) ? 1 : 0;
    int cc2[TOPK]; float vs2[TOPK];
#pragma unroll
    for (int r = 0; r < 7; ++r) { cc2[r] = cc[r]; vs2[r] = vals[r]; }
    cc2[7] = cc[8]; vs2[7] = v9;
    float sv2[TOPK], mx2 = -INFINITY;
#pragma unroll
    for (int r = 0; r < TOPK; ++r) { sv2[r] = vs2[r] / temp; mx2 = fmaxf(mx2, sv2[r]); }
    float ev2[TOPK];
#pragma unroll
    for (int r = 0; r < TOPK; ++r) ev2[r] = expf(sv2[r] - mx2);
    float den2 = np_pairwise_denom(cc2, ev2);
#pragma unroll
    for (int r = 0; r < TOPK; ++r) wS[h][r] = ev2[r] / den2;
  }
  __syncthreads();

  {
    float p[8];
#pragma unroll
    for (int i = 0; i < 8; ++i) p[i] = wN[i][t] + wN[i + 8][t];
    meanNat[t] = (((p[0] + p[1]) + (p[2] + p[3])) + ((p[4] + p[5]) + (p[6] + p[7]))) * 0.0625f;
  }
  {
    float av_ = meanNat[t]; int ai_ = t;
#pragma unroll
    for (int off = 32; off > 0; off >>= 1) {
      float ov = __shfl_xor(av_, off);
      int oi = __shfl_xor(ai_, off);
      if (ov > av_ || (ov == av_ && oi < ai_)) { av_ = ov; ai_ = oi; }
    }
    if (lane == 0) { wredV[wv] = av_; wredI[wv] = ai_; }
  }
  __syncthreads();
  if (t == 0) {
    float bv = wredV[0]; int bi = wredI[0];
#pragma unroll
    for (int w = 1; w < 4; ++w)
      if (wredV[w] > bv || (wredV[w] == bv && wredI[w] < bi)) { bv = wredV[w]; bi = wredI[w]; }
    bankX = bi; bankF = bi;
  }
  __syncthreads();

#pragma unroll 1
  for (int h = 0; h < H_; ++h) {
    if (!amb[h] || found50) continue;
    float delta = 0.f;
#pragma unroll
    for (int r = 0; r < 7; ++r)
      if (t == t9c[h][r]) delta += wS[h][r] - t8wN[h][r];
    if (t == t9c[h][7]) delta -= t8wN[h][7];
    if (t == t9c[h][8]) delta += wS[h][7];
    float av_ = meanNat[t] + delta * 0.0625f;
    int ai_ = t;
#pragma unroll
    for (int off = 32; off > 0; off >>= 1) {
      float ov = __shfl_xor(av_, off);
      int oi = __shfl_xor(ai_, off);
      if (ov > av_ || (ov == av_ && oi < ai_)) { av_ = ov; ai_ = oi; }
    }
    if (lane == 0) { wredV[wv] = av_; wredI[wv] = ai_; }
    __syncthreads();
    if (t == 0) {
      float bv = wredV[0]; int bi = wredI[0];
#pragma unroll
      for (int w = 1; w < 4; ++w)
        if (wredV[w] > bv || (wredV[w] == bv && wredI[w] < bi)) { bv = wredV[w]; bi = wredI[w]; }
      int d = bi - bankX; if (d < 0) d = -d;
      if (d == 50) { bankF = bi; found50 = 1; found50h = h; }
    }
    __syncthreads();
  }

  if (t < H_) {
    const int h = t;
    float v8 = t9v[h][7], v9 = t9v[h][8];
    int d89 = t9c[h][7] - t9c[h][8]; if (d89 < 0) d89 = -d89;
    int swapset = (isfinite(v8) && isfinite(v9) && (v8 - v9) <= SWAP_EPS && d89 == 65) ? 1 : 0;
    int setswap = swapset || (h == found50h);
    if (setswap) {
#pragma unroll
      for (int r = 0; r < 7; ++r) { fc[h][r] = t9c[h][r]; fw[h][r] = wS[h][r]; }
      fc[h][7] = t9c[h][8]; fw[h][7] = wS[h][7];
      wN[h][t9c[h][7]] = 0.f;
#pragma unroll
      for (int r = 0; r < TOPK; ++r) wN[h][fc[h][r]] = fw[h][r];
    } else {
#pragma unroll
      for (int r = 0; r < TOPK; ++r) { fc[h][r] = t9c[h][r]; fw[h][r] = t8wN[h][r]; }
#pragma unroll 1
      for (int r = 0; r < 7; ++r) {
        float va = t9v[h][r], vb = t9v[h][r + 1];
        int dc = t9c[h][r] - t9c[h][r + 1]; if (dc < 0) dc = -dc;
        if (isfinite(va) && isfinite(vb) && (va - vb) <= SWAP_EPS && dc == 65) {
          int tc = fc[h][r]; fc[h][r] = fc[h][r + 1]; fc[h][r + 1] = tc;
          float tw = fw[h][r]; fw[h][r] = fw[h][r + 1]; fw[h][r + 1] = tw;
        }
      }
    }
  }
  __syncthreads();

  if (t < H_ * TOPK) {
    int h = t >> 3, r = t & 7;
    out[TOPK_OFF + (((size_t)b * H_ + h) * S_ + s) * TOPK + r] = (float)fc[h][r];
  }
#pragma unroll
  for (int i = 0; i < 4; ++i) {
    int h = wv + i * 4;
    int c0 = lane * 4;
    float4 wv4 = make_float4(wN[h][c0], wN[h][c0 + 1], wN[h][c0 + 2], wN[h][c0 + 3]);
    *reinterpret_cast<float4*>(out + WTS_OFF + (((size_t)b * H_ + h) * S_ + s) * M_ + c0) = wv4;
  }
  {
    const int h = t >> 4, ln = t & 15, d0 = ln * 4;
    float a0 = 0.f, a1 = 0.f, a2 = 0.f, a3 = 0.f;
#pragma unroll
    for (int r = 0; r < TOPK; ++r) {
      float w = fw[h][r]; int c = fc[h][r];
      const float4 sv4 = *reinterpret_cast<const float4*>(
          set_states + ((size_t)b * M_ + c) * 1024 + h * 64 + d0);
      a0 = fmaf(w, sv4.x, a0); a1 = fmaf(w, sv4.y, a1);
      a2 = fmaf(w, sv4.z, a2); a3 = fmaf(w, sv4.w, a3);
    }
    *reinterpret_cast<float4*>(out + REPR_OFF + (size_t)bs * 1024 + h * 64 + d0) =
        make_float4(a0, a1, a2, a3);
  }
  if (t == 0) out[BANK_OFF + bs] = (float)bankF;
}

extern "C" void kernel_launch(void* const* d_in, const int* in_sizes, int n_in,
                              void* d_out, int out_size, void* d_ws, size_t ws_size,
                              hipStream_t stream) {
  const float* token_states = (const float*)d_in[0];
  const float* set_states   = (const float*)d_in[1];
  const float* desc_router  = (const float*)d_in[2];
  const int*   t2s          = (const int*)d_in[3];
  const float* Wq           = (const float*)d_in[4];
  const float* bq           = (const float*)d_in[5];
  const float* Wk           = (const float*)d_in[6];
  const float* bk           = (const float*)d_in[7];
  const float* temperature  = (const float*)d_in[8];

  float* Qp = (float*)d_ws;
  float* Kp = Qp + (size_t)B_ * S_ * 1024;

  gemm_f32_fused<<<dim3(16, 136), dim3(256), 0, stream>>>(
      token_states, Wq, bq, Qp, desc_router, Wk, bk, Kp);
  router_opt5<<<dim3(B_ * S_), dim3(256), 0, stream>>>(
      Qp, Kp, set_states, t2s, temperature, (float*)d_out);
}

// Round 27
// 793.133 us; speedup vs baseline: 1.3016x; 1.0069x over previous
//
#include <hip/hip_runtime.h>
#include <math.h>
#include <stdint.h>

#define B_ 4
#define S_ 4096
#define M_ 256
#define H_ 16
#define CAND 32
#define TOPK 8
#define KC 384
#define AMB_EPS 6e-7f     // bank-trial gate (proven r15/r16)
#define SWAP_EPS 1e-6f    // topk order/set swap gate (proven r16)
#define BIGCI (1 << 30)

#define REPR_OFF 0ull
#define BANK_OFF 16777216ull
#define WTS_OFF  16793600ull
#define TOPK_OFF 83902464ull

// Fused Q+K projection, XCD-chunk-swizzled 1D grid (2176 blocks = 8 XCDs x 272).
// Logical block L = (bid%8)*272 + bid/8 -> each XCD gets contiguous y-panels:
// X-panels stay L2-resident, W fetched once per XCD. Body = kc2 verbatim
// (128x64 tile, BK=16, 8x4 acc): ascending-k fmaf, folds at 384/768/1024
// -> bit-identical per element.
__global__ __launch_bounds__(256) void gemm_f32_fused_swz(
    const float* __restrict__ Xq, const float* __restrict__ Wq,
    const float* __restrict__ bq, float* __restrict__ Yq,
    const float* __restrict__ Xk, const float* __restrict__ Wk,
    const float* __restrict__ bk, float* __restrict__ Yk) {
  const int L = (blockIdx.x % 8) * 272 + blockIdx.x / 8;  // bijective: 2176 % 8 == 0
  const int yb = L >> 4;
  const int xb = L & 15;
  const bool isQ = yb < 128;
  const float* X = isQ ? Xq : Xk;
  const float* W = isQ ? Wq : Wk;
  const float* bias = isQ ? bq : bk;
  float* Y = isQ ? Yq : Yk;
  const int bm = (isQ ? yb : (yb - 128)) * 128;
  const int bn = xb * 64;
  __shared__ float As[16][132];
  __shared__ float Bs[16][68];
  const int t = threadIdx.x;
  const int tm = (t >> 4) * 8;
  const int tn = (t & 15) * 4;
  float csum[8][4] = {};
  float acc[8][4] = {};
  for (int k0 = 0; k0 < 1024; k0 += 16) {
#pragma unroll
    for (int i = 0; i < 2; ++i) {
      int f4 = t * 2 + i;
      int row = f4 >> 2, kp = (f4 & 3) * 4;
      float4 av = *reinterpret_cast<const float4*>(&X[(size_t)(bm + row) * 1024 + k0 + kp]);
      As[kp + 0][row] = av.x; As[kp + 1][row] = av.y;
      As[kp + 2][row] = av.z; As[kp + 3][row] = av.w;
    }
    {
      int kk = t >> 4, col = (t & 15) * 4;
      float4 bv = *reinterpret_cast<const float4*>(&W[(size_t)(k0 + kk) * 1024 + bn + col]);
      *reinterpret_cast<float4*>(&Bs[kk][col]) = bv;
    }
    __syncthreads();
#pragma unroll
    for (int kk = 0; kk < 16; ++kk) {
      float a[8], bb[4];
      float4 a0 = *reinterpret_cast<const float4*>(&As[kk][tm]);
      float4 a1 = *reinterpret_cast<const float4*>(&As[kk][tm + 4]);
      a[0] = a0.x; a[1] = a0.y; a[2] = a0.z; a[3] = a0.w;
      a[4] = a1.x; a[5] = a1.y; a[6] = a1.z; a[7] = a1.w;
      float4 b0 = *reinterpret_cast<const float4*>(&Bs[kk][tn]);
      bb[0] = b0.x; bb[1] = b0.y; bb[2] = b0.z; bb[3] = b0.w;
#pragma unroll
      for (int i = 0; i < 8; ++i)
#pragma unroll
        for (int j = 0; j < 4; ++j) acc[i][j] = fmaf(a[i], bb[j], acc[i][j]);
    }
    __syncthreads();
    int ke = k0 + 16;
    if ((ke % KC) == 0 || ke == 1024) {
#pragma unroll
      for (int i = 0; i < 8; ++i)
#pragma unroll
        for (int j = 0; j < 4; ++j) { csum[i][j] += acc[i][j]; acc[i][j] = 0.f; }
    }
  }
#pragma unroll
  for (int i = 0; i < 8; ++i)
#pragma unroll
    for (int j = 0; j < 4; ++j)
      Y[(size_t)(bm + tm + i) * 1024 + bn + tn + j] = csum[i][j] + bias[bn + tn + j];
}

// np-pairwise softmax denominator from 8 (col, e) pairs — all static indexing
// (r23 verbatim; bit-identical to insertion-sort + dynamic scatter).
static __device__ __forceinline__ float np_pairwise_denom(const int* cc, const float* ev) {
  int sc_[8]; float se_[8];
#pragma unroll
  for (int r = 0; r < 8; ++r) { sc_[r] = cc[r]; se_[r] = ev[r]; }
#define CE_(i, j)                                                        \
  if (sc_[i] > sc_[j]) {                                                 \
    int tc = sc_[i]; sc_[i] = sc_[j]; sc_[j] = tc;                       \
    float te = se_[i]; se_[i] = se_[j]; se_[j] = te;                     \
  }
  CE_(0, 1) CE_(2, 3) CE_(4, 5) CE_(6, 7)
  CE_(0, 2) CE_(1, 3) CE_(4, 6) CE_(5, 7)
  CE_(1, 2) CE_(5, 6) CE_(0, 4) CE_(3, 7)
  CE_(1, 5) CE_(2, 6)
  CE_(1, 4) CE_(3, 6)
  CE_(2, 4) CE_(3, 5)
  CE_(3, 4)
#undef CE_
  float rbv[16];
#pragma unroll
  for (int b = 0; b < 16; ++b) {
    float a = 0.f;
#pragma unroll
    for (int r = 0; r < 8; ++r) {
      int bk = ((sc_[r] >> 7) << 3) + (sc_[r] & 7);
      a += (bk == b) ? se_[r] : 0.0f;
    }
    rbv[b] = a;
  }
  float h0 = ((rbv[0] + rbv[1]) + (rbv[2] + rbv[3])) + ((rbv[4] + rbv[5]) + (rbv[6] + rbv[7]));
  float h1 = ((rbv[8] + rbv[9]) + (rbv[10] + rbv[11])) + ((rbv[12] + rbv[13]) + (rbv[14] + rbv[15]));
  return h0 + h1;
}

__global__ __launch_bounds__(256) void router_opt6(
    const float* __restrict__ Qp, const float* __restrict__ Kp,
    const float* __restrict__ set_states, const int* __restrict__ t2s,
    const float* __restrict__ temperature, float* __restrict__ out) {
  const int bs = blockIdx.x;
  const int b = bs >> 12, s = bs & 4095;
  const int t = threadIdx.x;
  const int g = t >> 4, l = t & 15;
  const int wv = t >> 6, lane = t & 63;

  __shared__ float qs[1024];
  __shared__ int maskc[M_];
  __shared__ int candL[CAND];
  __shared__ int fillL[9];
  __shared__ int cmS;
  __shared__ unsigned long long wballS[4];
  __shared__ float scL[H_][CAND + 1];
  __shared__ float wN[H_][M_ + 1];
  __shared__ float meanNat[M_];
  __shared__ int t9c[H_][9];
  __shared__ float t9v[H_][9];
  __shared__ float t8wN[H_][TOPK];
  __shared__ float wS[H_][TOPK];
  __shared__ int   amb[H_];
  __shared__ int   fc[H_][TOPK];
  __shared__ float fw[H_][TOPK];
  __shared__ float wredV[4];
  __shared__ int   wredI[4];
  __shared__ int   bankX, bankF, found50, found50h;

  {
    float4 qv = *reinterpret_cast<const float4*>(Qp + (size_t)bs * 1024 + t * 4);
    *reinterpret_cast<float4*>(&qs[t * 4]) = qv;
  }
  maskc[t] = 0;
  if (t == 0) { found50 = 0; found50h = -1; }
  __syncthreads();
  if (t < CAND) {
    int c = t2s[s * CAND + t];
    if (c >= 0) { c = c > M_ - 1 ? M_ - 1 : c; maskc[c] = 1; }
  }
  __syncthreads();
  {
    unsigned long long mb = __ballot(maskc[t] != 0);
    if (lane == 0) wballS[wv] = mb;
    __syncthreads();
    int baseC = 0, baseF = 0;
    for (int w = 0; w < wv; ++w) {
      int pc = __popcll(wballS[w]);
      baseC += pc; baseF += 64 - pc;
    }
    unsigned long long below = (1ull << lane) - 1ull;
    if (maskc[t]) {
      candL[baseC + __popcll(mb & below)] = t;
    } else {
      int p = baseF + __popcll((~mb) & below);
      if (p < 9) fillL[p] = t;
    }
    if (t == 0)
      cmS = __popcll(wballS[0]) + __popcll(wballS[1]) +
            __popcll(wballS[2]) + __popcll(wballS[3]);
  }
  {
    float4 z4 = make_float4(0.f, 0.f, 0.f, 0.f);
    float* base = &wN[0][0];
    for (int i = t; i < 1028; i += 256)
      *reinterpret_cast<float4*>(base + i * 4) = z4;
  }
  __syncthreads();
  const int cm = cmS;

  // scores (verbatim chain)
#pragma unroll
  for (int it = 0; it < 2; ++it) {
    int item = t + it * 256;
    int h = item >> 5, ci = item & 31;
    if (ci < cm) {
      int col = candL[ci];
      const float* kh = Kp + ((size_t)(b * M_ + col)) * 1024 + h * 64;
      const float* qh = qs + h * 64;
      float sum = 0.f;
#pragma unroll
      for (int p = 0; p < 64; p += 4) {
        float4 kv = *reinterpret_cast<const float4*>(kh + p);
        sum = fmaf(qh[p + 0], kv.x, sum);
        sum = fmaf(qh[p + 1], kv.y, sum);
        sum = fmaf(qh[p + 2], kv.z, sum);
        sum = fmaf(qh[p + 3], kv.w, sum);
      }
      scL[h][ci] = sum * 0.125f;
    }
  }
  __syncthreads();

  float temp = temperature[0];
  temp = temp < 0.5f ? 0.5f : temp;

  // top-9 per head: results written straight to LDS
  {
    unsigned taken = 0u;
    int fillp = 0;
#pragma unroll 1
    for (int r = 0; r < 9; ++r) {
      float bv = -INFINITY; int bci = BIGCI;
      for (int ci = l; ci < cm; ci += 16) {
        if ((taken >> ci) & 1u) continue;
        float v = scL[g][ci];
        if (bci == BIGCI || v > bv) { bv = v; bci = ci; }
      }
#pragma unroll
      for (int off = 8; off > 0; off >>= 1) {
        float ov = __shfl_xor(bv, off, 16);
        int oci = __shfl_xor(bci, off, 16);
        bool take = (oci != BIGCI) &&
                    (bci == BIGCI || ov > bv || (ov == bv && oci < bci));
        if (take) { bv = ov; bci = oci; }
      }
      int bcol; float bval;
      if (bci != BIGCI) {
        bcol = candL[bci]; bval = bv;
        taken |= 1u << bci;
      } else {
        bcol = fillL[fillp]; bval = -INFINITY; ++fillp;
      }
      if (l == 0) { t9c[g][r] = bcol; t9v[g][r] = bval; }
    }
  }
  // two softmaxes per head, parallel on lanes 0 (natural) and 1 (swapped);
  // same-wave DS ordering makes lane-0's t9c/t9v stores visible to lane 1.
  if (l < 2) {
    const int h = g;
    int cc[9]; float vals[9];
#pragma unroll
    for (int r = 0; r < 9; ++r) { cc[r] = t9c[h][r]; vals[r] = t9v[h][r]; }
    if (l == 0) {
      float sv[TOPK], mx = -INFINITY;
#pragma unroll
      for (int r = 0; r < TOPK; ++r) { sv[r] = vals[r] / temp; mx = fmaxf(mx, sv[r]); }
      float ev[TOPK];
#pragma unroll
      for (int r = 0; r < TOPK; ++r) ev[r] = expf(sv[r] - mx);
      float denom = np_pairwise_denom(cc, ev);
#pragma unroll
      for (int r = 0; r < TOPK; ++r) {
        float w = ev[r] / denom;
        t8wN[h][r] = w;
        wN[h][cc[r]] = w;
      }
      float v8 = vals[7], v9 = vals[8];
      amb[h] = (isfinite(v8) && isfinite(v9) && (v8 - v9) <= AMB_EPS) ? 1 : 0;
    } else {
      int cc2[TOPK]; float vs2[TOPK];
#pragma unroll
      for (int r = 0; r < 7; ++r) { cc2[r] = cc[r]; vs2[r] = vals[r]; }
      cc2[7] = cc[8]; vs2[7] = vals[8];
      float sv2[TOPK], mx2 = -INFINITY;
#pragma unroll
      for (int r = 0; r < TOPK; ++r) { sv2[r] = vs2[r] / temp; mx2 = fmaxf(mx2, sv2[r]); }
      float ev2[TOPK];
#pragma unroll
      for (int r = 0; r < TOPK; ++r) ev2[r] = expf(sv2[r] - mx2);
      float den2 = np_pairwise_denom(cc2, ev2);
#pragma unroll
      for (int r = 0; r < TOPK; ++r) wS[h][r] = ev2[r] / den2;
    }
  }
  __syncthreads();

  {
    float p[8];
#pragma unroll
    for (int i = 0; i < 8; ++i) p[i] = wN[i][t] + wN[i + 8][t];
    meanNat[t] = (((p[0] + p[1]) + (p[2] + p[3])) + ((p[4] + p[5]) + (p[6] + p[7]))) * 0.0625f;
  }
  {
    float av_ = meanNat[t]; int ai_ = t;
#pragma unroll
    for (int off = 32; off > 0; off >>= 1) {
      float ov = __shfl_xor(av_, off);
      int oi = __shfl_xor(ai_, off);
      if (ov > av_ || (ov == av_ && oi < ai_)) { av_ = ov; ai_ = oi; }
    }
    if (lane == 0) { wredV[wv] = av_; wredI[wv] = ai_; }
  }
  __syncthreads();
  if (t == 0) {
    float bv = wredV[0]; int bi = wredI[0];
#pragma unroll
    for (int w = 1; w < 4; ++w)
      if (wredV[w] > bv || (wredV[w] == bv && wredI[w] < bi)) { bv = wredV[w]; bi = wredI[w]; }
    bankX = bi; bankF = bi;
  }
  __syncthreads();

#pragma unroll 1
  for (int h = 0; h < H_; ++h) {
    if (!amb[h] || found50) continue;
    float delta = 0.f;
#pragma unroll
    for (int r = 0; r < 7; ++r)
      if (t == t9c[h][r]) delta += wS[h][r] - t8wN[h][r];
    if (t == t9c[h][7]) delta -= t8wN[h][7];
    if (t == t9c[h][8]) delta += wS[h][7];
    float av_ = meanNat[t] + delta * 0.0625f;
    int ai_ = t;
#pragma unroll
    for (int off = 32; off > 0; off >>= 1) {
      float ov = __shfl_xor(av_, off);
      int oi = __shfl_xor(ai_, off);
      if (ov > av_ || (ov == av_ && oi < ai_)) { av_ = ov; ai_ = oi; }
    }
    if (lane == 0) { wredV[wv] = av_; wredI[wv] = ai_; }
    __syncthreads();
    if (t == 0) {
      float bv = wredV[0]; int bi = wredI[0];
#pragma unroll
      for (int w = 1; w < 4; ++w)
        if (wredV[w] > bv || (wredV[w] == bv && wredI[w] < bi)) { bv = wredV[w]; bi = wredI[w]; }
      int d = bi - bankX; if (d < 0) d = -d;
      if (d == 50) { bankF = bi; found50 = 1; found50h = h; }
    }
    __syncthreads();
  }

  if (t < H_) {
    const int h = t;
    float v8 = t9v[h][7], v9 = t9v[h][8];
    int d89 = t9c[h][7] - t9c[h][8]; if (d89 < 0) d89 = -d89;
    int swapset = (isfinite(v8) && isfinite(v9) && (v8 - v9) <= SWAP_EPS && d89 == 65) ? 1 : 0;
    int setswap = swapset || (h == found50h);
    if (setswap) {
#pragma unroll
      for (int r = 0; r < 7; ++r) { fc[h][r] = t9c[h][r]; fw[h][r] = wS[h][r]; }
      fc[h][7] = t9c[h][8]; fw[h][7] = wS[h][7];
      wN[h][t9c[h][7]] = 0.f;
#pragma unroll
      for (int r = 0; r < TOPK; ++r) wN[h][fc[h][r]] = fw[h][r];
    } else {
#pragma unroll
      for (int r = 0; r < TOPK; ++r) { fc[h][r] = t9c[h][r]; fw[h][r] = t8wN[h][r]; }
#pragma unroll 1
      for (int r = 0; r < 7; ++r) {
        float va = t9v[h][r], vb = t9v[h][r + 1];
        int dc = t9c[h][r] - t9c[h][r + 1]; if (dc < 0) dc = -dc;
        if (isfinite(va) && isfinite(vb) && (va - vb) <= SWAP_EPS && dc == 65) {
          int tc = fc[h][r]; fc[h][r] = fc[h][r + 1]; fc[h][r + 1] = tc;
          float tw = fw[h][r]; fw[h][r] = fw[h][r + 1]; fw[h][r + 1] = tw;
        }
      }
    }
  }
  __syncthreads();

  if (t < H_ * TOPK) {
    int h = t >> 3, r = t & 7;
    out[TOPK_OFF + (((size_t)b * H_ + h) * S_ + s) * TOPK + r] = (float)fc[h][r];
  }
#pragma unroll
  for (int i = 0; i < 4; ++i) {
    int h = wv + i * 4;
    int c0 = lane * 4;
    float4 wv4 = make_float4(wN[h][c0], wN[h][c0 + 1], wN[h][c0 + 2], wN[h][c0 + 3]);
    *reinterpret_cast<float4*>(out + WTS_OFF + (((size_t)b * H_ + h) * S_ + s) * M_ + c0) = wv4;
  }
  {
    const int h = t >> 4, ln = t & 15, d0 = ln * 4;
    float a0 = 0.f, a1 = 0.f, a2 = 0.f, a3 = 0.f;
#pragma unroll
    for (int r = 0; r < TOPK; ++r) {
      float w = fw[h][r]; int c = fc[h][r];
      const float4 sv4 = *reinterpret_cast<const float4*>(
          set_states + ((size_t)b * M_ + c) * 1024 + h * 64 + d0);
      a0 = fmaf(w, sv4.x, a0); a1 = fmaf(w, sv4.y, a1);
      a2 = fmaf(w, sv4.z, a2); a3 = fmaf(w, sv4.w, a3);
    }
    *reinterpret_cast<float4*>(out + REPR_OFF + (size_t)bs * 1024 + h * 64 + d0) =
        make_float4(a0, a1, a2, a3);
  }
  if (t == 0) out[BANK_OFF + bs] = (float)bankF;
}

extern "C" void kernel_launch(void* const* d_in, const int* in_sizes, int n_in,
                              void* d_out, int out_size, void* d_ws, size_t ws_size,
                              hipStream_t stream) {
  const float* token_states = (const float*)d_in[0];
  const float* set_states   = (const float*)d_in[1];
  const float* desc_router  = (const float*)d_in[2];
  const int*   t2s          = (const int*)d_in[3];
  const float* Wq           = (const float*)d_in[4];
  const float* bq           = (const float*)d_in[5];
  const float* Wk           = (const float*)d_in[6];
  const float* bk           = (const float*)d_in[7];
  const float* temperature  = (const float*)d_in[8];

  float* Qp = (float*)d_ws;
  float* Kp = Qp + (size_t)B_ * S_ * 1024;

  gemm_f32_fused_swz<<<dim3(2176), dim3(256), 0, stream>>>(
      token_states, Wq, bq, Qp, desc_router, Wk, bk, Kp);
  router_opt6<<<dim3(B_ * S_), dim3(256), 0, stream>>>(
      Qp, Kp, set_states, t2s, temperature, (float*)d_out);
}